// Round 4
// baseline (17308.369 us; speedup 1.0000x reference)
//
#include <hip/hip_runtime.h>
#include <math.h>

#define B_ 64
#define T_ 256
#define D_ 300
#define H_ 512
#define G4_ 2048   // 4*H
#define HD_ 1024   // 2*H
#define CH_ 64     // time chunk for xp precompute
#define NWG_ 64    // persistent kernel workgroups

typedef short s8v __attribute__((ext_vector_type(8)));   // 8 bf16 (4 VGPRs)
typedef float f32x4 __attribute__((ext_vector_type(4)));

__device__ inline unsigned short f2bf_rne(float f) {
  unsigned u = __builtin_bit_cast(unsigned, f);
  unsigned r = (u + 0x7fff + ((u >> 16) & 1)) >> 16;
  return (unsigned short)r;
}
__device__ inline float bf2f(unsigned short h) {
  unsigned u = ((unsigned)h) << 16;
  return __builtin_bit_cast(float, u);
}

// device-scope grid barrier: monotonic counter, reset per launch by memset.
__device__ inline void gridbar(unsigned* cnt, unsigned target) {
  __syncthreads();   // all waves' stores drained (vmcnt0 before s_barrier)
  if (threadIdx.x == 0) {
    __threadfence();  // release: flush this WG's h stores toward LLC
    __hip_atomic_fetch_add(cnt, 1u, __ATOMIC_RELEASE, __HIP_MEMORY_SCOPE_AGENT);
    while (__hip_atomic_load(cnt, __ATOMIC_ACQUIRE, __HIP_MEMORY_SCOPE_AGENT) < target) {
      __builtin_amdgcn_s_sleep(1);
    }
    __threadfence();  // acquire: invalidate L1/L2 before reading others' h
  }
  __syncthreads();
}

// ---------------- lengths ----------------
__global__ void k_lengths(const int* __restrict__ word, int* __restrict__ lens,
                          int* __restrict__ out_len) {
  __shared__ int s[256];
  int b = blockIdx.x, t = threadIdx.x;
  s[t] = (word[b * T_ + t] > 0) ? 1 : 0;
  __syncthreads();
  for (int off = 128; off > 0; off >>= 1) {
    if (t < off) s[t] += s[t + off];
    __syncthreads();
  }
  if (t == 0) { lens[b] = s[0]; out_len[b] = s[0]; }
}

// ---------------- embedding gather: x (T,B,D) ----------------
__global__ void k_embed(const int* __restrict__ word, const float* __restrict__ emb,
                        float* __restrict__ x) {
  const int D4 = D_ / 4;
  int idx = blockIdx.x * blockDim.x + threadIdx.x;
  if (idx >= T_ * B_ * D4) return;
  int d4 = idx % D4;
  int row = idx / D4;           // row = t*B + b
  int b = row % B_, t = row / B_;
  int w = word[b * T_ + t];
  float4 v = ((const float4*)(emb + (size_t)w * D_))[d4];
  ((float4*)(x + (size_t)row * D_))[d4] = v;
}

// ---------------- bf16 hi/lo split of weights ----------------
__global__ void k_split(const float* __restrict__ w, unsigned short* __restrict__ hi,
                        unsigned short* __restrict__ lo, int n) {
  int i = blockIdx.x * blockDim.x + threadIdx.x;
  if (i >= n) return;
  float f = w[i];
  unsigned short h = f2bf_rne(f);
  float r = f - bf2f(h);
  hi[i] = h;
  lo[i] = f2bf_rne(r);
}

// ---------------- projection GEMM: xp[(tl,2048,B)] = A * W^T + bias ----------------
// src: (T,B,K) t-major. If rev: A row (s,b) = src[len[b]-1-s] (zeros if <0).
// Block bm covers exactly one tl (64 batch rows), bn covers 64 cols.
// Output staged through LDS so the transposed store is coalesced.
__global__ __launch_bounds__(256) void k_proj(
    const float* __restrict__ src, const float* __restrict__ W,
    const float* __restrict__ bias, float* __restrict__ C,
    const int* __restrict__ lens, int K, int t0, int rev) {
  __shared__ float As[16][68];
  __shared__ float Ws[16][68];
  __shared__ float S[64][65];
  int bm = blockIdx.x, bn = blockIdx.y;
  int tid = threadIdx.x;
  int tx = tid & 15, ty = tid >> 4;
  float acc[4][4];
#pragma unroll
  for (int i = 0; i < 4; i++)
#pragma unroll
    for (int j = 0; j < 4; j++) acc[i][j] = 0.f;

  int lr = tid >> 2;        // 0..63
  int lk = (tid & 3) * 4;   // 0,4,8,12

  int b = lr;               // block bm covers rows tl=bm, b=0..63
  long srow;
  if (!rev) srow = (long)(t0 + bm) * B_ + b;
  else {
    int tp = lens[b] - 1 - (t0 + bm);
    srow = (tp >= 0) ? (long)tp * B_ + b : -1;
  }
  const float* arow = (srow >= 0) ? src + (size_t)srow * K : (const float*)0;
  int wcol = bn * 64 + lr;
  const float* wrow = W + (size_t)wcol * K;

  for (int k0 = 0; k0 < K; k0 += 16) {
    float4 av; av.x = av.y = av.z = av.w = 0.f;
    if (arow) {
      if (k0 + lk + 4 <= K) av = *(const float4*)(arow + k0 + lk);
      else {
        float tv[4] = {0.f, 0.f, 0.f, 0.f};
        for (int q = 0; q < 4; q++) if (k0 + lk + q < K) tv[q] = arow[k0 + lk + q];
        av.x = tv[0]; av.y = tv[1]; av.z = tv[2]; av.w = tv[3];
      }
    }
    float4 wv; wv.x = wv.y = wv.z = wv.w = 0.f;
    if (k0 + lk + 4 <= K) wv = *(const float4*)(wrow + k0 + lk);
    else {
      float tv[4] = {0.f, 0.f, 0.f, 0.f};
      for (int q = 0; q < 4; q++) if (k0 + lk + q < K) tv[q] = wrow[k0 + lk + q];
      wv.x = tv[0]; wv.y = tv[1]; wv.z = tv[2]; wv.w = tv[3];
    }
    __syncthreads();
    As[lk + 0][lr] = av.x; As[lk + 1][lr] = av.y; As[lk + 2][lr] = av.z; As[lk + 3][lr] = av.w;
    Ws[lk + 0][lr] = wv.x; Ws[lk + 1][lr] = wv.y; Ws[lk + 2][lr] = wv.z; Ws[lk + 3][lr] = wv.w;
    __syncthreads();
#pragma unroll
    for (int k = 0; k < 16; k++) {
      float4 a4 = *(const float4*)&As[k][ty * 4];
      float4 b4 = *(const float4*)&Ws[k][tx * 4];
      acc[0][0] += a4.x * b4.x; acc[0][1] += a4.x * b4.y; acc[0][2] += a4.x * b4.z; acc[0][3] += a4.x * b4.w;
      acc[1][0] += a4.y * b4.x; acc[1][1] += a4.y * b4.y; acc[1][2] += a4.y * b4.z; acc[1][3] += a4.y * b4.w;
      acc[2][0] += a4.z * b4.x; acc[2][1] += a4.z * b4.y; acc[2][2] += a4.z * b4.z; acc[2][3] += a4.z * b4.w;
      acc[3][0] += a4.w * b4.x; acc[3][1] += a4.w * b4.y; acc[3][2] += a4.w * b4.z; acc[3][3] += a4.w * b4.w;
    }
  }
  // stage to LDS transposed: S[col][b], then coalesced store to (tl, col, b)
  __syncthreads();
  float bsv[4];
#pragma unroll
  for (int j = 0; j < 4; j++) bsv[j] = bias[bn * 64 + tx * 4 + j];
#pragma unroll
  for (int i = 0; i < 4; i++)
#pragma unroll
    for (int j = 0; j < 4; j++)
      S[tx * 4 + j][ty * 4 + i] = acc[i][j] + bsv[j];
  __syncthreads();
  float* Cbase = C + ((size_t)bm * G4_ + (size_t)bn * 64) * B_;
#pragma unroll
  for (int it = 0; it < 4; it++) {
    int c = (tid >> 4) + it * 16;
    int b0 = (tid & 15) * 4;
    float4 v = *(const float4*)&S[c][b0];
    *(float4*)(Cbase + (size_t)c * B_ + b0) = v;
  }
}

// ---------------- persistent LSTM chunk: 64 steps, weights in VGPRs ----------------
// 64 WGs: wg>>5 = dir, (wg&31)*16 = u0. Wave = gate block. c in registers.
__global__ __launch_bounds__(256, 1) void k_lstm_chunk(
    const unsigned short* __restrict__ whh_hi, const unsigned short* __restrict__ whh_lo,
    const float* __restrict__ xpf, const float* __restrict__ xpr,
    const int* __restrict__ lens,
    unsigned short* __restrict__ hhi, unsigned short* __restrict__ hlo,  // [pp][dir][B][H]
    float* __restrict__ cbuf,                                            // [dir][B][H]
    float* __restrict__ out, int t0, unsigned* __restrict__ cnt) {
  int wg = blockIdx.x;
  int dir = wg >> 5;
  int u0 = (wg & 31) * 16;
  int tid = threadIdx.x;
  int g = tid >> 6;        // wave = gate block
  int lane = tid & 63;
  int lm = lane & 15;
  int kg = (lane >> 4) * 8;
  int n = g * H_ + u0 + lm;

  const unsigned short* Whi = whh_hi + (size_t)dir * G4_ * H_;
  const unsigned short* Wlo = whh_lo + (size_t)dir * G4_ * H_;
  const float* xpb = (dir == 0) ? xpf : xpr;

  __shared__ float gl[4 * 16 * 65];

  // preload weight fragments once per chunk (32 KB/wave -> 128 VGPRs)
  s8v bh[16], bl[16];
#pragma unroll
  for (int kt = 0; kt < 16; kt++) {
    bh[kt] = *(const s8v*)(Whi + (size_t)n * H_ + kt * 32 + kg);
    bl[kt] = *(const s8v*)(Wlo + (size_t)n * H_ + kt * 32 + kg);
  }

  // epilogue identity: thread owns (dir, b=eb, units u0+uq*4..+3)
  int eb = tid & 63;
  int uq = tid >> 6;
  int len = lens[eb];
  // local offset within one [B][H] h-plane (pp/dir applied via base pointers)
  size_t lhoff = (size_t)eb * H_ + u0 + uq * 4;
  // cbuf is [dir][B][H]: dir belongs in the offset here (and ONLY here)
  size_t coff = ((size_t)dir * B_ + eb) * H_ + u0 + uq * 4;
  float4 cv4 = *(const float4*)(cbuf + coff);
  float creg[4] = {cv4.x, cv4.y, cv4.z, cv4.w};

  for (int tl = 0; tl < CH_; tl++) {
    int t = t0 + tl;
    int pp = t & 1;
    const unsigned short* Hhi = hhi + ((size_t)(pp * 2 + dir)) * B_ * H_;
    const unsigned short* Hlo = hlo + ((size_t)(pp * 2 + dir)) * B_ * H_;
    unsigned short* Hho  = hhi + ((size_t)((pp ^ 1) * 2 + dir)) * B_ * H_;
    unsigned short* Hloo = hlo + ((size_t)((pp ^ 1) * 2 + dir)) * B_ * H_;
    const float* xp = xpb + (size_t)tl * G4_ * B_;

    f32x4 aH[4], aX[4];
#pragma unroll
    for (int bt = 0; bt < 4; bt++) {
      f32x4 z = {0.f, 0.f, 0.f, 0.f};
      aH[bt] = z; aX[bt] = z;
    }
#pragma unroll
    for (int kt = 0; kt < 16; kt++) {
#pragma unroll
      for (int bt = 0; bt < 4; bt++) {
        size_t abase = (size_t)(bt * 16 + lm) * H_ + kt * 32 + kg;
        s8v ah = *(const s8v*)(Hhi + abase);
        s8v al = *(const s8v*)(Hlo + abase);
        aH[bt] = __builtin_amdgcn_mfma_f32_16x16x32_bf16(ah, bh[kt], aH[bt], 0, 0, 0);
        aX[bt] = __builtin_amdgcn_mfma_f32_16x16x32_bf16(al, bh[kt], aX[bt], 0, 0, 0);
        aX[bt] = __builtin_amdgcn_mfma_f32_16x16x32_bf16(ah, bl[kt], aX[bt], 0, 0, 0);
      }
    }
    __syncthreads();   // previous step's epilogue reads of gl are done
#pragma unroll
    for (int bt = 0; bt < 4; bt++) {
#pragma unroll
      for (int jj = 0; jj < 4; jj++) {
        int brow = bt * 16 + (lane >> 4) * 4 + jj;
        gl[(g * 16 + lm) * 65 + brow] = aH[bt][jj] + aX[bt][jj];
      }
    }
    __syncthreads();

    // epilogue
    if (t < len) {
      float hn[4];
#pragma unroll
      for (int q = 0; q < 4; q++) {
        int ul = uq * 4 + q;
        int ug = u0 + ul;
        float iv = gl[(0 * 16 + ul) * 65 + eb] + xp[(size_t)(0 * H_ + ug) * B_ + eb];
        float fv = gl[(1 * 16 + ul) * 65 + eb] + xp[(size_t)(1 * H_ + ug) * B_ + eb];
        float gv = gl[(2 * 16 + ul) * 65 + eb] + xp[(size_t)(2 * H_ + ug) * B_ + eb];
        float ov = gl[(3 * 16 + ul) * 65 + eb] + xp[(size_t)(3 * H_ + ug) * B_ + eb];
        float si = 1.f / (1.f + expf(-iv));
        float sf = 1.f / (1.f + expf(-fv));
        float so = 1.f / (1.f + expf(-ov));
        float cn = sf * creg[q] + si * tanhf(gv);
        creg[q] = cn;
        hn[q] = so * tanhf(cn);
      }
      ushort4 hi4, lo4;
      unsigned short h0 = f2bf_rne(hn[0]); unsigned short l0 = f2bf_rne(hn[0] - bf2f(h0));
      unsigned short h1 = f2bf_rne(hn[1]); unsigned short l1 = f2bf_rne(hn[1] - bf2f(h1));
      unsigned short h2 = f2bf_rne(hn[2]); unsigned short l2 = f2bf_rne(hn[2] - bf2f(h2));
      unsigned short h3 = f2bf_rne(hn[3]); unsigned short l3 = f2bf_rne(hn[3] - bf2f(h3));
      hi4.x = h0; hi4.y = h1; hi4.z = h2; hi4.w = h3;
      lo4.x = l0; lo4.y = l1; lo4.z = l2; lo4.w = l3;
      *(ushort4*)(Hho + lhoff) = hi4;
      *(ushort4*)(Hloo + lhoff) = lo4;
      float4 hv; hv.x = hn[0]; hv.y = hn[1]; hv.z = hn[2]; hv.w = hn[3];
      if (dir == 0) *(float4*)(out + ((size_t)t * B_ + eb) * HD_ + u0 + uq * 4) = hv;
      else          *(float4*)(out + ((size_t)(len - 1 - t) * B_ + eb) * HD_ + H_ + u0 + uq * 4) = hv;
    } else {
      *(ushort4*)(Hho + lhoff)  = *(const ushort4*)(Hhi + lhoff);
      *(ushort4*)(Hloo + lhoff) = *(const ushort4*)(Hlo + lhoff);
      if (dir == 0) {
        float4 z; z.x = z.y = z.z = z.w = 0.f;
        *(float4*)(out + ((size_t)t * B_ + eb) * HD_ + u0 + uq * 4) = z;
      }
    }
    if (tl != CH_ - 1) gridbar(cnt, (unsigned)(tl + 1) * NWG_);
  }
  *(float4*)(cbuf + coff) = *(const float4*)creg;
}

// ---------------- emission heads ----------------
__global__ void k_em0(const float* __restrict__ o, const float* __restrict__ w,
                      const float* __restrict__ bias, float* __restrict__ em) {
  int gt = blockIdx.x * blockDim.x + threadIdx.x;
  int wid = gt >> 6;
  int lane = threadIdx.x & 63;
  if (wid >= T_ * B_) return;
  const float* row = o + (size_t)wid * HD_;
  float r[16];
#pragma unroll
  for (int q = 0; q < 16; q++) r[q] = row[lane + 64 * q];
  for (int c = 0; c < 13; c++) {
    const float* wr = w + (size_t)c * HD_;
    float p = 0.f;
#pragma unroll
    for (int q = 0; q < 16; q++) p += r[q] * wr[lane + 64 * q];
    for (int off = 32; off > 0; off >>= 1) p += __shfl_down(p, off);
    if (lane == 0) em[(size_t)wid * 16 + c] = p + bias[c];
  }
}

__global__ void k_em1(const float* __restrict__ o, const float* __restrict__ w,
                      const float* __restrict__ bias, const int* __restrict__ tags0,
                      float* __restrict__ em) {
  int gt = blockIdx.x * blockDim.x + threadIdx.x;
  int wid = gt >> 6;
  int lane = threadIdx.x & 63;
  if (wid >= T_ * B_) return;
  int t = wid / B_, b = wid % B_;
  float tag = (float)tags0[b * T_ + t];
  const float* row = o + (size_t)wid * HD_;
  float r[16];
#pragma unroll
  for (int q = 0; q < 16; q++) r[q] = row[lane + 64 * q];
  for (int c = 0; c < 25; c++) {
    const float* wr = w + (size_t)c * 1025;
    float p = 0.f;
#pragma unroll
    for (int q = 0; q < 16; q++) p += r[q] * wr[lane + 64 * q];
    for (int off = 32; off > 0; off >>= 1) p += __shfl_down(p, off);
    if (lane == 0) em[(size_t)wid * 32 + c] = p + wr[1024] * tag + bias[c];
  }
}

// ---------------- Viterbi (one block per batch element) ----------------
template <int L, int LD>
__global__ void k_viterbi(const float* __restrict__ em, const int* __restrict__ lens,
                          const float* __restrict__ startv, const float* __restrict__ endv,
                          const float* __restrict__ trans, int* __restrict__ hist,
                          int* __restrict__ tags) {
  int b = blockIdx.x;
  int j = threadIdx.x;
  __shared__ float sc[L];
  __shared__ float trT[L * L];
  int len = lens[b];
  if (j < L) {
    sc[j] = startv[j] + em[(size_t)b * LD + j];
    for (int i = 0; i < L; i++) trT[j * L + i] = trans[i * L + j];
  }
  __syncthreads();
  for (int t = 1; t < len; t++) {
    float nv = 0.f; int bi = 0;
    if (j < L) {
      float best = sc[0] + trT[j * L + 0];
      for (int i = 1; i < L; i++) {
        float v = sc[i] + trT[j * L + i];
        if (v > best) { best = v; bi = i; }
      }
      nv = best + em[((size_t)t * B_ + b) * LD + j];
      hist[((size_t)b * T_ + t) * LD + j] = bi;
    }
    __syncthreads();
    if (j < L) sc[j] = nv;
    __syncthreads();
  }
  if (j == 0) {
    float best = sc[0] + endv[0]; int bi = 0;
    for (int i = 1; i < L; i++) {
      float v = sc[i] + endv[i];
      if (v > best) { best = v; bi = i; }
    }
    int tag = bi;
    tags[b * T_ + (len - 1)] = tag;
    for (int t = len - 2; t >= 0; t--) {
      tag = hist[((size_t)b * T_ + (t + 1)) * LD + tag];
      tags[b * T_ + t] = tag;
    }
    for (int t = len; t < T_; t++) tags[b * T_ + t] = 0;
  }
}

// ---------------- host ----------------
extern "C" void kernel_launch(void* const* d_in, const int* in_sizes, int n_in,
                              void* d_out, int out_size, void* d_ws, size_t ws_size,
                              hipStream_t stream) {
  const int*   word = (const int*)d_in[0];
  const float* emb  = (const float*)d_in[1];
  const float* w0ih = (const float*)d_in[2];
  const float* w0hh = (const float*)d_in[3];
  const float* b0   = (const float*)d_in[4];
  const float* w1ih = (const float*)d_in[5];
  const float* w1hh = (const float*)d_in[6];
  const float* b1   = (const float*)d_in[7];
  const float* h0w  = (const float*)d_in[8];
  const float* h0b  = (const float*)d_in[9];
  const float* h1w  = (const float*)d_in[10];
  const float* h1b  = (const float*)d_in[11];
  const float* c0s  = (const float*)d_in[12];
  const float* c0e  = (const float*)d_in[13];
  const float* c0t  = (const float*)d_in[14];
  const float* c1s  = (const float*)d_in[15];
  const float* c1e  = (const float*)d_in[16];
  const float* c1t  = (const float*)d_in[17];

  int* out_tags0 = (int*)d_out;
  int* out_tags1 = out_tags0 + B_ * T_;
  int* out_len   = out_tags1 + B_ * T_;

  char* ws = (char*)d_ws;
  size_t off = 0;
  auto alloc = [&](size_t bytes) -> void* {
    void* p = ws + off;
    off += (bytes + 255) & ~(size_t)255;
    return p;
  };
  int*   lens  = (int*)alloc(B_ * 4);
  unsigned* cnt = (unsigned*)alloc(256);
  float* x     = (float*)alloc((size_t)T_ * B_ * D_ * 4);
  float* out0  = (float*)alloc((size_t)T_ * B_ * HD_ * 4);
  float* out1  = (float*)alloc((size_t)T_ * B_ * HD_ * 4);
  float* xpf   = (float*)alloc((size_t)CH_ * B_ * G4_ * 4);
  float* xpr   = (float*)alloc((size_t)CH_ * B_ * G4_ * 4);
  unsigned short* hhi = (unsigned short*)alloc((size_t)2 * 2 * B_ * H_ * 2);  // pingpong x dir
  unsigned short* hlo = (unsigned short*)alloc((size_t)2 * 2 * B_ * H_ * 2);
  float* cbuf  = (float*)alloc((size_t)2 * B_ * H_ * 4);
  unsigned short* w0hh_hi = (unsigned short*)alloc((size_t)2 * G4_ * H_ * 2);
  unsigned short* w0hh_lo = (unsigned short*)alloc((size_t)2 * G4_ * H_ * 2);
  unsigned short* w1hh_hi = (unsigned short*)alloc((size_t)2 * G4_ * H_ * 2);
  unsigned short* w1hh_lo = (unsigned short*)alloc((size_t)2 * G4_ * H_ * 2);
  float* em0   = (float*)alloc((size_t)T_ * B_ * 16 * 4);
  float* em1   = (float*)alloc((size_t)T_ * B_ * 32 * 4);
  int*   hist0 = (int*)alloc((size_t)B_ * T_ * 16 * 4);
  int*   hist1 = (int*)alloc((size_t)B_ * T_ * 32 * 4);
  (void)ws_size; (void)in_sizes; (void)n_in; (void)out_size;

  hipMemsetAsync(out0, 0, (size_t)T_ * B_ * HD_ * 4, stream);
  hipMemsetAsync(out1, 0, (size_t)T_ * B_ * HD_ * 4, stream);

  k_lengths<<<B_, 256, 0, stream>>>(word, lens, out_len);
  {
    int total = T_ * B_ * (D_ / 4);
    k_embed<<<(total + 255) / 256, 256, 0, stream>>>(word, emb, x);
  }
  {
    int n = 2 * G4_ * H_;
    k_split<<<(n + 255) / 256, 256, 0, stream>>>(w0hh, w0hh_hi, w0hh_lo, n);
    k_split<<<(n + 255) / 256, 256, 0, stream>>>(w1hh, w1hh_hi, w1hh_lo, n);
  }

  for (int layer = 0; layer < 2; layer++) {
    const float* src = (layer == 0) ? x : out0;
    int K = (layer == 0) ? D_ : HD_;
    const float* wih = (layer == 0) ? w0ih : w1ih;
    const float* bb  = (layer == 0) ? b0 : b1;
    const unsigned short* whi = (layer == 0) ? w0hh_hi : w1hh_hi;
    const unsigned short* wlo = (layer == 0) ? w0hh_lo : w1hh_lo;
    float* outbuf = (layer == 0) ? out0 : out1;
    hipMemsetAsync(hhi, 0, (size_t)2 * 2 * B_ * H_ * 2, stream);
    hipMemsetAsync(hlo, 0, (size_t)2 * 2 * B_ * H_ * 2, stream);
    hipMemsetAsync(cbuf, 0, (size_t)2 * B_ * H_ * 4, stream);
    for (int cch = 0; cch < T_ / CH_; cch++) {
      dim3 grid(CH_, G4_ / 64);
      k_proj<<<grid, 256, 0, stream>>>(src, wih, bb, xpf, lens, K, cch * CH_, 0);
      k_proj<<<grid, 256, 0, stream>>>(src, wih + (size_t)G4_ * K, bb + G4_, xpr, lens, K, cch * CH_, 1);
      hipMemsetAsync(cnt, 0, 4, stream);
      k_lstm_chunk<<<NWG_, 256, 0, stream>>>(whi, wlo, xpf, xpr, lens, hhi, hlo,
                                             cbuf, outbuf, cch * CH_, cnt);
    }
  }

  k_em0<<<(T_ * B_) / 4, 256, 0, stream>>>(out1, h0w, h0b, em0);
  k_viterbi<13, 16><<<B_, 64, 0, stream>>>(em0, lens, c0s, c0e, c0t, hist0, out_tags0);
  k_em1<<<(T_ * B_) / 4, 256, 0, stream>>>(out1, h1w, h1b, out_tags0, em1);
  k_viterbi<25, 32><<<B_, 64, 0, stream>>>(em1, lens, c1s, c1e, c1t, hist1, out_tags1);
}

// Round 5
// 9907.001 us; speedup vs baseline: 1.7471x; 1.7471x over previous
//
#include <hip/hip_runtime.h>
#include <math.h>

#define B_ 64
#define T_ 256
#define D_ 300
#define H_ 512
#define G4_ 2048   // 4*H
#define HD_ 1024   // 2*H
#define CH_ 64     // time chunk for xp precompute
#define NWG_ 64    // persistent kernel workgroups

typedef short s8v __attribute__((ext_vector_type(8)));   // 8 bf16 (4 VGPRs)
typedef float f32x4 __attribute__((ext_vector_type(4)));
typedef __attribute__((address_space(1))) const char GChar;
typedef __attribute__((address_space(3))) char LChar;

// h planes are stored SWIZZLED in global: byte ^= ((b&7)<<4). Both writer and
// reader apply it; global_load_lds copies the image linearly into LDS and the
// ds_read side applies the same XOR -> 2-way (free) bank conflicts instead of 16-way.
#define HSWZ(lby, b) ((lby) ^ ((size_t)((b) & 7) << 4))

__device__ inline unsigned short f2bf_rne(float f) {
  unsigned u = __builtin_bit_cast(unsigned, f);
  unsigned r = (u + 0x7fff + ((u >> 16) & 1)) >> 16;
  return (unsigned short)r;
}
__device__ inline float bf2f(unsigned short h) {
  unsigned u = ((unsigned)h) << 16;
  return __builtin_bit_cast(float, u);
}

// device-scope grid barrier: monotonic counter, reset per launch by memset.
// RELAXED atomics + explicit fences (ACQUIRE-per-poll caused cache maintenance per spin).
__device__ inline void gridbar(unsigned* cnt, unsigned target) {
  __syncthreads();   // all waves' stores drained (vmcnt0 before s_barrier)
  if (threadIdx.x == 0) {
    __threadfence();  // release: L2 writeback of this WG's h stores
    __hip_atomic_fetch_add(cnt, 1u, __ATOMIC_RELAXED, __HIP_MEMORY_SCOPE_AGENT);
    while (__hip_atomic_load(cnt, __ATOMIC_RELAXED, __HIP_MEMORY_SCOPE_AGENT) < target) {
      __builtin_amdgcn_s_sleep(1);
    }
    __threadfence();  // acquire: invalidate L1/L2 before reading others' h
  }
  __syncthreads();
}

// ---------------- lengths ----------------
__global__ void k_lengths(const int* __restrict__ word, int* __restrict__ lens,
                          int* __restrict__ out_len) {
  __shared__ int s[256];
  int b = blockIdx.x, t = threadIdx.x;
  s[t] = (word[b * T_ + t] > 0) ? 1 : 0;
  __syncthreads();
  for (int off = 128; off > 0; off >>= 1) {
    if (t < off) s[t] += s[t + off];
    __syncthreads();
  }
  if (t == 0) { lens[b] = s[0]; out_len[b] = s[0]; }
}

// ---------------- embedding gather: x (T,B,D) ----------------
__global__ void k_embed(const int* __restrict__ word, const float* __restrict__ emb,
                        float* __restrict__ x) {
  const int D4 = D_ / 4;
  int idx = blockIdx.x * blockDim.x + threadIdx.x;
  if (idx >= T_ * B_ * D4) return;
  int d4 = idx % D4;
  int row = idx / D4;           // row = t*B + b
  int b = row % B_, t = row / B_;
  int w = word[b * T_ + t];
  float4 v = ((const float4*)(emb + (size_t)w * D_))[d4];
  ((float4*)(x + (size_t)row * D_))[d4] = v;
}

// ---------------- bf16 hi/lo split of weights ----------------
__global__ void k_split(const float* __restrict__ w, unsigned short* __restrict__ hi,
                        unsigned short* __restrict__ lo, int n) {
  int i = blockIdx.x * blockDim.x + threadIdx.x;
  if (i >= n) return;
  float f = w[i];
  unsigned short h = f2bf_rne(f);
  float r = f - bf2f(h);
  hi[i] = h;
  lo[i] = f2bf_rne(r);
}

// ---------------- projection GEMM: xp[(tl,2048,B)] = A * W^T + bias ----------------
// src: (T,B,K) t-major. If rev: A row (s,b) = src[len[b]-1-s] (zeros if <0).
// Block bm covers exactly one tl (64 batch rows), bn covers 64 cols.
// Output staged through LDS so the transposed store is coalesced.
__global__ __launch_bounds__(256) void k_proj(
    const float* __restrict__ src, const float* __restrict__ W,
    const float* __restrict__ bias, float* __restrict__ C,
    const int* __restrict__ lens, int K, int t0, int rev) {
  __shared__ float As[16][68];
  __shared__ float Ws[16][68];
  __shared__ float S[64][65];
  int bm = blockIdx.x, bn = blockIdx.y;
  int tid = threadIdx.x;
  int tx = tid & 15, ty = tid >> 4;
  float acc[4][4];
#pragma unroll
  for (int i = 0; i < 4; i++)
#pragma unroll
    for (int j = 0; j < 4; j++) acc[i][j] = 0.f;

  int lr = tid >> 2;        // 0..63
  int lk = (tid & 3) * 4;   // 0,4,8,12

  int b = lr;               // block bm covers rows tl=bm, b=0..63
  long srow;
  if (!rev) srow = (long)(t0 + bm) * B_ + b;
  else {
    int tp = lens[b] - 1 - (t0 + bm);
    srow = (tp >= 0) ? (long)tp * B_ + b : -1;
  }
  const float* arow = (srow >= 0) ? src + (size_t)srow * K : (const float*)0;
  int wcol = bn * 64 + lr;
  const float* wrow = W + (size_t)wcol * K;

  for (int k0 = 0; k0 < K; k0 += 16) {
    float4 av; av.x = av.y = av.z = av.w = 0.f;
    if (arow) {
      if (k0 + lk + 4 <= K) av = *(const float4*)(arow + k0 + lk);
      else {
        float tv[4] = {0.f, 0.f, 0.f, 0.f};
        for (int q = 0; q < 4; q++) if (k0 + lk + q < K) tv[q] = arow[k0 + lk + q];
        av.x = tv[0]; av.y = tv[1]; av.z = tv[2]; av.w = tv[3];
      }
    }
    float4 wv; wv.x = wv.y = wv.z = wv.w = 0.f;
    if (k0 + lk + 4 <= K) wv = *(const float4*)(wrow + k0 + lk);
    else {
      float tv[4] = {0.f, 0.f, 0.f, 0.f};
      for (int q = 0; q < 4; q++) if (k0 + lk + q < K) tv[q] = wrow[k0 + lk + q];
      wv.x = tv[0]; wv.y = tv[1]; wv.z = tv[2]; wv.w = tv[3];
    }
    __syncthreads();
    As[lk + 0][lr] = av.x; As[lk + 1][lr] = av.y; As[lk + 2][lr] = av.z; As[lk + 3][lr] = av.w;
    Ws[lk + 0][lr] = wv.x; Ws[lk + 1][lr] = wv.y; Ws[lk + 2][lr] = wv.z; Ws[lk + 3][lr] = wv.w;
    __syncthreads();
#pragma unroll
    for (int k = 0; k < 16; k++) {
      float4 a4 = *(const float4*)&As[k][ty * 4];
      float4 b4 = *(const float4*)&Ws[k][tx * 4];
      acc[0][0] += a4.x * b4.x; acc[0][1] += a4.x * b4.y; acc[0][2] += a4.x * b4.z; acc[0][3] += a4.x * b4.w;
      acc[1][0] += a4.y * b4.x; acc[1][1] += a4.y * b4.y; acc[1][2] += a4.y * b4.z; acc[1][3] += a4.y * b4.w;
      acc[2][0] += a4.z * b4.x; acc[2][1] += a4.z * b4.y; acc[2][2] += a4.z * b4.z; acc[2][3] += a4.z * b4.w;
      acc[3][0] += a4.w * b4.x; acc[3][1] += a4.w * b4.y; acc[3][2] += a4.w * b4.z; acc[3][3] += a4.w * b4.w;
    }
  }
  // stage to LDS transposed: S[col][b], then coalesced store to (tl, col, b)
  __syncthreads();
  float bsv[4];
#pragma unroll
  for (int j = 0; j < 4; j++) bsv[j] = bias[bn * 64 + tx * 4 + j];
#pragma unroll
  for (int i = 0; i < 4; i++)
#pragma unroll
    for (int j = 0; j < 4; j++)
      S[tx * 4 + j][ty * 4 + i] = acc[i][j] + bsv[j];
  __syncthreads();
  float* Cbase = C + ((size_t)bm * G4_ + (size_t)bn * 64) * B_;
#pragma unroll
  for (int it = 0; it < 4; it++) {
    int c = (tid >> 4) + it * 16;
    int b0 = (tid & 15) * 4;
    float4 v = *(const float4*)&S[c][b0];
    *(float4*)(Cbase + (size_t)c * B_ + b0) = v;
  }
}

// ---------------- persistent LSTM chunk: 64 steps, weights in VGPRs ----------------
// 64 WGs: wg>>5 = dir, (wg&31)*16 = u0. Wave = gate block. c in registers.
// h planes staged into LDS (async) each step; xp prefetched into regs a step ahead.
__global__ __launch_bounds__(256, 1) void k_lstm_chunk(
    const unsigned short* __restrict__ whh_hi, const unsigned short* __restrict__ whh_lo,
    const float* __restrict__ xpf, const float* __restrict__ xpr,
    const int* __restrict__ lens,
    unsigned short* __restrict__ hhi, unsigned short* __restrict__ hlo,  // [pp][dir][B][H] (swizzled image)
    float* __restrict__ cbuf,                                            // [dir][B][H]
    float* __restrict__ out, int t0, unsigned* __restrict__ cnt) {
  int wg = blockIdx.x;
  int dir = wg >> 5;
  int u0 = (wg & 31) * 16;
  int tid = threadIdx.x;
  int g = tid >> 6;        // wave = gate block
  int lane = tid & 63;
  int lm = lane & 15;
  int kb = (lane >> 4) * 16;     // byte offset of this lane's 8-elem k-group
  int n = g * H_ + u0 + lm;

  const unsigned short* Whi = whh_hi + (size_t)dir * G4_ * H_;
  const unsigned short* Wlo = whh_lo + (size_t)dir * G4_ * H_;
  const float* xpb = (dir == 0) ? xpf : xpr;

  // 128 KB: [0,64K) = swizzled h_hi image, [64K,128K) = h_lo image.
  // glx (16.6 KB gate exchange) ALIASES the front: all fragment reads complete
  // (barrier) before glx is written each step.
  __shared__ char lbuf[131072];
  float* glx = (float*)lbuf;

  // preload weight fragments once per chunk (32 KB/wave -> 128 VGPRs)
  s8v bh[16], bl[16];
#pragma unroll
  for (int kt = 0; kt < 16; kt++) {
    bh[kt] = *(const s8v*)(Whi + (size_t)n * H_ + kt * 32 + (kb >> 1));
    bl[kt] = *(const s8v*)(Wlo + (size_t)n * H_ + kt * 32 + (kb >> 1));
  }

  // epilogue identity: thread owns (dir, b=eb, units u0+uq*4..+3)
  int eb = tid & 63;
  int uq = tid >> 6;
  int len = lens[eb];
  size_t lby = (size_t)eb * 1024 + (size_t)(u0 + uq * 4) * 2;  // logical byte in h plane
  size_t pby = HSWZ(lby, eb);                                   // swizzled byte
  size_t coff = ((size_t)dir * B_ + eb) * H_ + u0 + uq * 4;
  float4 cv4 = *(const float4*)(cbuf + coff);
  float creg[4] = {cv4.x, cv4.y, cv4.z, cv4.w};

  // xp prefetch for tl=0
  float xq[16];
#pragma unroll
  for (int q2 = 0; q2 < 16; q2++) {
    int gg = q2 >> 2, qq = q2 & 3;
    xq[q2] = xpb[(size_t)(gg * H_ + u0 + uq * 4 + qq) * B_ + eb];
  }

  for (int tl = 0; tl < CH_; tl++) {
    int t = t0 + tl;
    int pp = t & 1;
    const char* srcHi = (const char*)(hhi + (size_t)(pp * 2 + dir) * B_ * H_);
    const char* srcLo = (const char*)(hlo + (size_t)(pp * 2 + dir) * B_ * H_);
    char* dstHi = (char*)(hhi + (size_t)((pp ^ 1) * 2 + dir) * B_ * H_);
    char* dstLo = (char*)(hlo + (size_t)((pp ^ 1) * 2 + dir) * B_ * H_);

    // ---- async stage h (hi+lo) into LDS: linear copy of the swizzled image ----
    {
      int sof = g * 16384 + lane * 16;
#pragma unroll
      for (int it = 0; it < 16; it++) {
        __builtin_amdgcn_global_load_lds((GChar*)(srcHi + sof + it * 1024),
                                         (LChar*)(lbuf + sof + it * 1024), 16, 0, 0);
        __builtin_amdgcn_global_load_lds((GChar*)(srcLo + sof + it * 1024),
                                         (LChar*)(lbuf + 65536 + sof + it * 1024), 16, 0, 0);
      }
    }
    __syncthreads();   // drains vmcnt(0): all waves' staging complete

    // ---- prefetch next step's xp into regs (independent of h; lands during MFMA) ----
    float xqn[16];
    if (tl < CH_ - 1) {
      const float* xpn = xpb + (size_t)(tl + 1) * G4_ * B_;
#pragma unroll
      for (int q2 = 0; q2 < 16; q2++) {
        int gg = q2 >> 2, qq = q2 & 3;
        xqn[q2] = xpn[(size_t)(gg * H_ + u0 + uq * 4 + qq) * B_ + eb];
      }
    }

    // ---- MFMA from LDS ----
    f32x4 aH[4], aX[4];
#pragma unroll
    for (int bt = 0; bt < 4; bt++) {
      f32x4 z = {0.f, 0.f, 0.f, 0.f};
      aH[bt] = z; aX[bt] = z;
    }
#pragma unroll
    for (int kt = 0; kt < 16; kt++) {
#pragma unroll
      for (int bt = 0; bt < 4; bt++) {
        int row = bt * 16 + lm;
        int p = (row * 1024 + kt * 64 + kb) ^ ((lm & 7) << 4);
        s8v ah = *(const s8v*)(lbuf + p);
        s8v al = *(const s8v*)(lbuf + 65536 + p);
        aH[bt] = __builtin_amdgcn_mfma_f32_16x16x32_bf16(ah, bh[kt], aH[bt], 0, 0, 0);
        aX[bt] = __builtin_amdgcn_mfma_f32_16x16x32_bf16(al, bh[kt], aX[bt], 0, 0, 0);
        aX[bt] = __builtin_amdgcn_mfma_f32_16x16x32_bf16(ah, bl[kt], aX[bt], 0, 0, 0);
      }
    }
    __syncthreads();   // all fragment reads done -> safe to overwrite front of lbuf (glx)
#pragma unroll
    for (int bt = 0; bt < 4; bt++) {
#pragma unroll
      for (int jj = 0; jj < 4; jj++) {
        int brow = bt * 16 + (lane >> 4) * 4 + jj;
        glx[(g * 16 + lm) * 65 + brow] = aH[bt][jj] + aX[bt][jj];
      }
    }
    __syncthreads();

    // ---- epilogue ----
    if (t < len) {
      float hn[4];
#pragma unroll
      for (int q = 0; q < 4; q++) {
        int ul = uq * 4 + q;
        float iv = glx[(0 * 16 + ul) * 65 + eb] + xq[0 * 4 + q];
        float fv = glx[(1 * 16 + ul) * 65 + eb] + xq[1 * 4 + q];
        float gv = glx[(2 * 16 + ul) * 65 + eb] + xq[2 * 4 + q];
        float ov = glx[(3 * 16 + ul) * 65 + eb] + xq[3 * 4 + q];
        float si = 1.f / (1.f + expf(-iv));
        float sf = 1.f / (1.f + expf(-fv));
        float so = 1.f / (1.f + expf(-ov));
        float cn = sf * creg[q] + si * tanhf(gv);
        creg[q] = cn;
        hn[q] = so * tanhf(cn);
      }
      ushort4 hi4, lo4;
      unsigned short h0 = f2bf_rne(hn[0]); unsigned short l0 = f2bf_rne(hn[0] - bf2f(h0));
      unsigned short h1 = f2bf_rne(hn[1]); unsigned short l1 = f2bf_rne(hn[1] - bf2f(h1));
      unsigned short h2 = f2bf_rne(hn[2]); unsigned short l2 = f2bf_rne(hn[2] - bf2f(h2));
      unsigned short h3 = f2bf_rne(hn[3]); unsigned short l3 = f2bf_rne(hn[3] - bf2f(h3));
      hi4.x = h0; hi4.y = h1; hi4.z = h2; hi4.w = h3;
      lo4.x = l0; lo4.y = l1; lo4.z = l2; lo4.w = l3;
      *(ushort4*)(dstHi + pby) = hi4;
      *(ushort4*)(dstLo + pby) = lo4;
      float4 hv; hv.x = hn[0]; hv.y = hn[1]; hv.z = hn[2]; hv.w = hn[3];
      if (dir == 0) *(float4*)(out + ((size_t)t * B_ + eb) * HD_ + u0 + uq * 4) = hv;
      else          *(float4*)(out + ((size_t)(len - 1 - t) * B_ + eb) * HD_ + H_ + u0 + uq * 4) = hv;
    } else {
      *(ushort4*)(dstHi + pby) = *(const ushort4*)(srcHi + pby);
      *(ushort4*)(dstLo + pby) = *(const ushort4*)(srcLo + pby);
      if (dir == 0) {
        float4 z; z.x = z.y = z.z = z.w = 0.f;
        *(float4*)(out + ((size_t)t * B_ + eb) * HD_ + u0 + uq * 4) = z;
      }
    }
#pragma unroll
    for (int q2 = 0; q2 < 16; q2++) xq[q2] = xqn[q2];
    if (tl != CH_ - 1) gridbar(cnt, (unsigned)(tl + 1) * NWG_);
  }
  *(float4*)(cbuf + coff) = *(const float4*)creg;
}

// ---------------- emission heads ----------------
__global__ void k_em0(const float* __restrict__ o, const float* __restrict__ w,
                      const float* __restrict__ bias, float* __restrict__ em) {
  int gt = blockIdx.x * blockDim.x + threadIdx.x;
  int wid = gt >> 6;
  int lane = threadIdx.x & 63;
  if (wid >= T_ * B_) return;
  const float* row = o + (size_t)wid * HD_;
  float r[16];
#pragma unroll
  for (int q = 0; q < 16; q++) r[q] = row[lane + 64 * q];
  for (int c = 0; c < 13; c++) {
    const float* wr = w + (size_t)c * HD_;
    float p = 0.f;
#pragma unroll
    for (int q = 0; q < 16; q++) p += r[q] * wr[lane + 64 * q];
    for (int off = 32; off > 0; off >>= 1) p += __shfl_down(p, off);
    if (lane == 0) em[(size_t)wid * 16 + c] = p + bias[c];
  }
}

__global__ void k_em1(const float* __restrict__ o, const float* __restrict__ w,
                      const float* __restrict__ bias, const int* __restrict__ tags0,
                      float* __restrict__ em) {
  int gt = blockIdx.x * blockDim.x + threadIdx.x;
  int wid = gt >> 6;
  int lane = threadIdx.x & 63;
  if (wid >= T_ * B_) return;
  int t = wid / B_, b = wid % B_;
  float tag = (float)tags0[b * T_ + t];
  const float* row = o + (size_t)wid * HD_;
  float r[16];
#pragma unroll
  for (int q = 0; q < 16; q++) r[q] = row[lane + 64 * q];
  for (int c = 0; c < 25; c++) {
    const float* wr = w + (size_t)c * 1025;
    float p = 0.f;
#pragma unroll
    for (int q = 0; q < 16; q++) p += r[q] * wr[lane + 64 * q];
    for (int off = 32; off > 0; off >>= 1) p += __shfl_down(p, off);
    if (lane == 0) em[(size_t)wid * 32 + c] = p + wr[1024] * tag + bias[c];
  }
}

// ---------------- Viterbi (one block per batch element) ----------------
template <int L, int LD>
__global__ void k_viterbi(const float* __restrict__ em, const int* __restrict__ lens,
                          const float* __restrict__ startv, const float* __restrict__ endv,
                          const float* __restrict__ trans, int* __restrict__ hist,
                          int* __restrict__ tags) {
  int b = blockIdx.x;
  int j = threadIdx.x;
  __shared__ float sc[L];
  __shared__ float trT[L * L];
  int len = lens[b];
  if (j < L) {
    sc[j] = startv[j] + em[(size_t)b * LD + j];
    for (int i = 0; i < L; i++) trT[j * L + i] = trans[i * L + j];
  }
  __syncthreads();
  for (int t = 1; t < len; t++) {
    float nv = 0.f; int bi = 0;
    if (j < L) {
      float best = sc[0] + trT[j * L + 0];
      for (int i = 1; i < L; i++) {
        float v = sc[i] + trT[j * L + i];
        if (v > best) { best = v; bi = i; }
      }
      nv = best + em[((size_t)t * B_ + b) * LD + j];
      hist[((size_t)b * T_ + t) * LD + j] = bi;
    }
    __syncthreads();
    if (j < L) sc[j] = nv;
    __syncthreads();
  }
  if (j == 0) {
    float best = sc[0] + endv[0]; int bi = 0;
    for (int i = 1; i < L; i++) {
      float v = sc[i] + endv[i];
      if (v > best) { best = v; bi = i; }
    }
    int tag = bi;
    tags[b * T_ + (len - 1)] = tag;
    for (int t = len - 2; t >= 0; t--) {
      tag = hist[((size_t)b * T_ + (t + 1)) * LD + tag];
      tags[b * T_ + t] = tag;
    }
    for (int t = len; t < T_; t++) tags[b * T_ + t] = 0;
  }
}

// ---------------- host ----------------
extern "C" void kernel_launch(void* const* d_in, const int* in_sizes, int n_in,
                              void* d_out, int out_size, void* d_ws, size_t ws_size,
                              hipStream_t stream) {
  const int*   word = (const int*)d_in[0];
  const float* emb  = (const float*)d_in[1];
  const float* w0ih = (const float*)d_in[2];
  const float* w0hh = (const float*)d_in[3];
  const float* b0   = (const float*)d_in[4];
  const float* w1ih = (const float*)d_in[5];
  const float* w1hh = (const float*)d_in[6];
  const float* b1   = (const float*)d_in[7];
  const float* h0w  = (const float*)d_in[8];
  const float* h0b  = (const float*)d_in[9];
  const float* h1w  = (const float*)d_in[10];
  const float* h1b  = (const float*)d_in[11];
  const float* c0s  = (const float*)d_in[12];
  const float* c0e  = (const float*)d_in[13];
  const float* c0t  = (const float*)d_in[14];
  const float* c1s  = (const float*)d_in[15];
  const float* c1e  = (const float*)d_in[16];
  const float* c1t  = (const float*)d_in[17];

  int* out_tags0 = (int*)d_out;
  int* out_tags1 = out_tags0 + B_ * T_;
  int* out_len   = out_tags1 + B_ * T_;

  char* ws = (char*)d_ws;
  size_t off = 0;
  auto alloc = [&](size_t bytes) -> void* {
    void* p = ws + off;
    off += (bytes + 255) & ~(size_t)255;
    return p;
  };
  int*   lens  = (int*)alloc(B_ * 4);
  unsigned* cnt = (unsigned*)alloc(256);
  float* x     = (float*)alloc((size_t)T_ * B_ * D_ * 4);
  float* out0  = (float*)alloc((size_t)T_ * B_ * HD_ * 4);
  float* out1  = (float*)alloc((size_t)T_ * B_ * HD_ * 4);
  float* xpf   = (float*)alloc((size_t)CH_ * B_ * G4_ * 4);
  float* xpr   = (float*)alloc((size_t)CH_ * B_ * G4_ * 4);
  unsigned short* hhi = (unsigned short*)alloc((size_t)2 * 2 * B_ * H_ * 2);  // pingpong x dir
  unsigned short* hlo = (unsigned short*)alloc((size_t)2 * 2 * B_ * H_ * 2);
  float* cbuf  = (float*)alloc((size_t)2 * B_ * H_ * 4);
  unsigned short* w0hh_hi = (unsigned short*)alloc((size_t)2 * G4_ * H_ * 2);
  unsigned short* w0hh_lo = (unsigned short*)alloc((size_t)2 * G4_ * H_ * 2);
  unsigned short* w1hh_hi = (unsigned short*)alloc((size_t)2 * G4_ * H_ * 2);
  unsigned short* w1hh_lo = (unsigned short*)alloc((size_t)2 * G4_ * H_ * 2);
  float* em0   = (float*)alloc((size_t)T_ * B_ * 16 * 4);
  float* em1   = (float*)alloc((size_t)T_ * B_ * 32 * 4);
  int*   hist0 = (int*)alloc((size_t)B_ * T_ * 16 * 4);
  int*   hist1 = (int*)alloc((size_t)B_ * T_ * 32 * 4);
  (void)ws_size; (void)in_sizes; (void)n_in; (void)out_size;

  hipMemsetAsync(out0, 0, (size_t)T_ * B_ * HD_ * 4, stream);
  hipMemsetAsync(out1, 0, (size_t)T_ * B_ * HD_ * 4, stream);

  k_lengths<<<B_, 256, 0, stream>>>(word, lens, out_len);
  {
    int total = T_ * B_ * (D_ / 4);
    k_embed<<<(total + 255) / 256, 256, 0, stream>>>(word, emb, x);
  }
  {
    int n = 2 * G4_ * H_;
    k_split<<<(n + 255) / 256, 256, 0, stream>>>(w0hh, w0hh_hi, w0hh_lo, n);
    k_split<<<(n + 255) / 256, 256, 0, stream>>>(w1hh, w1hh_hi, w1hh_lo, n);
  }

  for (int layer = 0; layer < 2; layer++) {
    const float* src = (layer == 0) ? x : out0;
    int K = (layer == 0) ? D_ : HD_;
    const float* wih = (layer == 0) ? w0ih : w1ih;
    const float* bb  = (layer == 0) ? b0 : b1;
    const unsigned short* whi = (layer == 0) ? w0hh_hi : w1hh_hi;
    const unsigned short* wlo = (layer == 0) ? w0hh_lo : w1hh_lo;
    float* outbuf = (layer == 0) ? out0 : out1;
    hipMemsetAsync(hhi, 0, (size_t)2 * 2 * B_ * H_ * 2, stream);
    hipMemsetAsync(hlo, 0, (size_t)2 * 2 * B_ * H_ * 2, stream);
    hipMemsetAsync(cbuf, 0, (size_t)2 * B_ * H_ * 4, stream);
    for (int cch = 0; cch < T_ / CH_; cch++) {
      dim3 grid(CH_, G4_ / 64);
      k_proj<<<grid, 256, 0, stream>>>(src, wih, bb, xpf, lens, K, cch * CH_, 0);
      k_proj<<<grid, 256, 0, stream>>>(src, wih + (size_t)G4_ * K, bb + G4_, xpr, lens, K, cch * CH_, 1);
      hipMemsetAsync(cnt, 0, 4, stream);
      k_lstm_chunk<<<NWG_, 256, 0, stream>>>(whi, wlo, xpf, xpr, lens, hhi, hlo,
                                             cbuf, outbuf, cch * CH_, cnt);
    }
  }

  k_em0<<<(T_ * B_) / 4, 256, 0, stream>>>(out1, h0w, h0b, em0);
  k_viterbi<13, 16><<<B_, 64, 0, stream>>>(em0, lens, c0s, c0e, c0t, hist0, out_tags0);
  k_em1<<<(T_ * B_) / 4, 256, 0, stream>>>(out1, h1w, h1b, out_tags0, em1);
  k_viterbi<25, 32><<<B_, 64, 0, stream>>>(em1, lens, c1s, c1e, c1t, hist1, out_tags1);
}

// Round 6
// 8576.764 us; speedup vs baseline: 2.0181x; 1.1551x over previous
//
#include <hip/hip_runtime.h>
#include <math.h>

#define B_ 64
#define T_ 256
#define D_ 300
#define H_ 512
#define G4_ 2048   // 4*H
#define HD_ 1024   // 2*H
#define CH_ 64     // time chunk for xp precompute
#define NWG_ 64    // persistent kernel workgroups

typedef short s8v __attribute__((ext_vector_type(8)));   // 8 bf16 (4 VGPRs)
typedef float f32x4 __attribute__((ext_vector_type(4)));
typedef __attribute__((address_space(1))) const char GChar;
typedef __attribute__((address_space(3))) char LChar;

// h planes stored SWIZZLED in global: byte ^= ((b&15)<<4). Writer (8B atomic
// stores) and reader (ds_read after linear global_load_lds copy) both apply it.
// 16 rows spread over 16 distinct 16B slots per 256B -> b128 reads at the
// 2-accesses/bank minimum (was (b&7): lanes 8-15 duplicated lanes 0-7 -> 8.9M conflicts).
#define HSWZ(lby, b) ((lby) ^ ((size_t)((b) & 15) << 4))

__device__ inline unsigned short f2bf_rne(float f) {
  unsigned u = __builtin_bit_cast(unsigned, f);
  unsigned r = (u + 0x7fff + ((u >> 16) & 1)) >> 16;
  return (unsigned short)r;
}
__device__ inline float bf2f(unsigned short h) {
  unsigned u = ((unsigned)h) << 16;
  return __builtin_bit_cast(float, u);
}

// Distributed flag barrier. h-stores are device-scope (sc1) so they are
// LLC-visible once vmcnt retires -- which __syncthreads() guarantees per wave.
// No threadfence => no buffer_wbl2/buffer_inv (the R5 L2-nuke, 2x/step).
// flags[wg] monotonic within a dispatch; memset to 0 before each launch.
__device__ inline void gridbar(unsigned* flags, int wg, unsigned target) {
  __syncthreads();   // all waves arrived; their vm stores retired (vmcnt0 before s_barrier)
  if (threadIdx.x < 64) {
    if (threadIdx.x == 0)
      __hip_atomic_store(flags + wg, target, __ATOMIC_RELAXED, __HIP_MEMORY_SCOPE_AGENT);
    while (true) {
      unsigned v = __hip_atomic_load(flags + threadIdx.x, __ATOMIC_RELAXED, __HIP_MEMORY_SCOPE_AGENT);
      if (__all((int)(v >= target))) break;
      __builtin_amdgcn_s_sleep(1);
    }
  }
  __syncthreads();
}

// ---------------- lengths ----------------
__global__ void k_lengths(const int* __restrict__ word, int* __restrict__ lens,
                          int* __restrict__ out_len) {
  __shared__ int s[256];
  int b = blockIdx.x, t = threadIdx.x;
  s[t] = (word[b * T_ + t] > 0) ? 1 : 0;
  __syncthreads();
  for (int off = 128; off > 0; off >>= 1) {
    if (t < off) s[t] += s[t + off];
    __syncthreads();
  }
  if (t == 0) { lens[b] = s[0]; out_len[b] = s[0]; }
}

// ---------------- embedding gather: x (T,B,D) ----------------
__global__ void k_embed(const int* __restrict__ word, const float* __restrict__ emb,
                        float* __restrict__ x) {
  const int D4 = D_ / 4;
  int idx = blockIdx.x * blockDim.x + threadIdx.x;
  if (idx >= T_ * B_ * D4) return;
  int d4 = idx % D4;
  int row = idx / D4;           // row = t*B + b
  int b = row % B_, t = row / B_;
  int w = word[b * T_ + t];
  float4 v = ((const float4*)(emb + (size_t)w * D_))[d4];
  ((float4*)(x + (size_t)row * D_))[d4] = v;
}

// ---------------- bf16 hi/lo split of weights ----------------
__global__ void k_split(const float* __restrict__ w, unsigned short* __restrict__ hi,
                        unsigned short* __restrict__ lo, int n) {
  int i = blockIdx.x * blockDim.x + threadIdx.x;
  if (i >= n) return;
  float f = w[i];
  unsigned short h = f2bf_rne(f);
  float r = f - bf2f(h);
  hi[i] = h;
  lo[i] = f2bf_rne(r);
}

// ---------------- projection GEMM: xp[(tl,2048,B)] = A * W^T + bias ----------------
// src: (T,B,K) t-major. If rev: A row (s,b) = src[len[b]-1-s] (zeros if <0).
// Block bm covers exactly one tl (64 batch rows), bn covers 64 cols.
// Output staged through LDS so the transposed store is coalesced.
__global__ __launch_bounds__(256) void k_proj(
    const float* __restrict__ src, const float* __restrict__ W,
    const float* __restrict__ bias, float* __restrict__ C,
    const int* __restrict__ lens, int K, int t0, int rev) {
  __shared__ float As[16][68];
  __shared__ float Ws[16][68];
  __shared__ float S[64][65];
  int bm = blockIdx.x, bn = blockIdx.y;
  int tid = threadIdx.x;
  int tx = tid & 15, ty = tid >> 4;
  float acc[4][4];
#pragma unroll
  for (int i = 0; i < 4; i++)
#pragma unroll
    for (int j = 0; j < 4; j++) acc[i][j] = 0.f;

  int lr = tid >> 2;        // 0..63
  int lk = (tid & 3) * 4;   // 0,4,8,12

  int b = lr;               // block bm covers rows tl=bm, b=0..63
  long srow;
  if (!rev) srow = (long)(t0 + bm) * B_ + b;
  else {
    int tp = lens[b] - 1 - (t0 + bm);
    srow = (tp >= 0) ? (long)tp * B_ + b : -1;
  }
  const float* arow = (srow >= 0) ? src + (size_t)srow * K : (const float*)0;
  int wcol = bn * 64 + lr;
  const float* wrow = W + (size_t)wcol * K;

  for (int k0 = 0; k0 < K; k0 += 16) {
    float4 av; av.x = av.y = av.z = av.w = 0.f;
    if (arow) {
      if (k0 + lk + 4 <= K) av = *(const float4*)(arow + k0 + lk);
      else {
        float tv[4] = {0.f, 0.f, 0.f, 0.f};
        for (int q = 0; q < 4; q++) if (k0 + lk + q < K) tv[q] = arow[k0 + lk + q];
        av.x = tv[0]; av.y = tv[1]; av.z = tv[2]; av.w = tv[3];
      }
    }
    float4 wv; wv.x = wv.y = wv.z = wv.w = 0.f;
    if (k0 + lk + 4 <= K) wv = *(const float4*)(wrow + k0 + lk);
    else {
      float tv[4] = {0.f, 0.f, 0.f, 0.f};
      for (int q = 0; q < 4; q++) if (k0 + lk + q < K) tv[q] = wrow[k0 + lk + q];
      wv.x = tv[0]; wv.y = tv[1]; wv.z = tv[2]; wv.w = tv[3];
    }
    __syncthreads();
    As[lk + 0][lr] = av.x; As[lk + 1][lr] = av.y; As[lk + 2][lr] = av.z; As[lk + 3][lr] = av.w;
    Ws[lk + 0][lr] = wv.x; Ws[lk + 1][lr] = wv.y; Ws[lk + 2][lr] = wv.z; Ws[lk + 3][lr] = wv.w;
    __syncthreads();
#pragma unroll
    for (int k = 0; k < 16; k++) {
      float4 a4 = *(const float4*)&As[k][ty * 4];
      float4 b4 = *(const float4*)&Ws[k][tx * 4];
      acc[0][0] += a4.x * b4.x; acc[0][1] += a4.x * b4.y; acc[0][2] += a4.x * b4.z; acc[0][3] += a4.x * b4.w;
      acc[1][0] += a4.y * b4.x; acc[1][1] += a4.y * b4.y; acc[1][2] += a4.y * b4.z; acc[1][3] += a4.y * b4.w;
      acc[2][0] += a4.z * b4.x; acc[2][1] += a4.z * b4.y; acc[2][2] += a4.z * b4.z; acc[2][3] += a4.z * b4.w;
      acc[3][0] += a4.w * b4.x; acc[3][1] += a4.w * b4.y; acc[3][2] += a4.w * b4.z; acc[3][3] += a4.w * b4.w;
    }
  }
  // stage to LDS transposed: S[col][b], then coalesced store to (tl, col, b)
  __syncthreads();
  float bsv[4];
#pragma unroll
  for (int j = 0; j < 4; j++) bsv[j] = bias[bn * 64 + tx * 4 + j];
#pragma unroll
  for (int i = 0; i < 4; i++)
#pragma unroll
    for (int j = 0; j < 4; j++)
      S[tx * 4 + j][ty * 4 + i] = acc[i][j] + bsv[j];
  __syncthreads();
  float* Cbase = C + ((size_t)bm * G4_ + (size_t)bn * 64) * B_;
#pragma unroll
  for (int it = 0; it < 4; it++) {
    int c = (tid >> 4) + it * 16;
    int b0 = (tid & 15) * 4;
    float4 v = *(const float4*)&S[c][b0];
    *(float4*)(Cbase + (size_t)c * B_ + b0) = v;
  }
}

// ---------------- persistent LSTM chunk: 64 steps, weights in VGPRs ----------------
// 64 WGs: wg>>5 = dir, (wg&31)*16 = u0. Wave = gate block. c in registers.
// h exchanged via device-scope (sc1) stores/loads -- no cache-wide maintenance.
__global__ __launch_bounds__(256, 1) void k_lstm_chunk(
    const unsigned short* __restrict__ whh_hi, const unsigned short* __restrict__ whh_lo,
    const float* __restrict__ xpf, const float* __restrict__ xpr,
    const int* __restrict__ lens,
    unsigned short* __restrict__ hhi, unsigned short* __restrict__ hlo,  // [pp][dir][B][H] (swizzled image)
    float* __restrict__ cbuf,                                            // [dir][B][H]
    float* __restrict__ out, int t0, unsigned* __restrict__ flags) {
  int wg = blockIdx.x;
  int dir = wg >> 5;
  int u0 = (wg & 31) * 16;
  int tid = threadIdx.x;
  int g = tid >> 6;        // wave = gate block
  int lane = tid & 63;
  int lm = lane & 15;
  int kb = (lane >> 4) * 16;     // byte offset of this lane's 8-elem k-group
  int n = g * H_ + u0 + lm;

  const unsigned short* Whi = whh_hi + (size_t)dir * G4_ * H_;
  const unsigned short* Wlo = whh_lo + (size_t)dir * G4_ * H_;
  const float* xpb = (dir == 0) ? xpf : xpr;

  // 128 KB: [0,64K) = swizzled h_hi image, [64K,128K) = h_lo image.
  // glx (16.6 KB gate exchange) ALIASES the front: all fragment reads complete
  // (barrier) before glx is written each step.
  __shared__ char lbuf[131072];
  float* glx = (float*)lbuf;

  // preload weight fragments once per chunk (32 KB/wave -> 128 VGPRs)
  s8v bh[16], bl[16];
#pragma unroll
  for (int kt = 0; kt < 16; kt++) {
    bh[kt] = *(const s8v*)(Whi + (size_t)n * H_ + kt * 32 + (kb >> 1));
    bl[kt] = *(const s8v*)(Wlo + (size_t)n * H_ + kt * 32 + (kb >> 1));
  }

  // epilogue identity: thread owns (dir, b=eb, units u0+uq*4..+3)
  int eb = tid & 63;
  int uq = tid >> 6;
  int len = lens[eb];
  size_t lby = (size_t)eb * 1024 + (size_t)(u0 + uq * 4) * 2;  // logical byte in h plane
  size_t pby = HSWZ(lby, eb);                                   // swizzled byte (8B aligned)
  size_t coff = ((size_t)dir * B_ + eb) * H_ + u0 + uq * 4;
  float4 cv4 = *(const float4*)(cbuf + coff);
  float creg[4] = {cv4.x, cv4.y, cv4.z, cv4.w};

  // xp prefetch for tl=0
  float xq[16];
#pragma unroll
  for (int q2 = 0; q2 < 16; q2++) {
    int gg = q2 >> 2, qq = q2 & 3;
    xq[q2] = xpb[(size_t)(gg * H_ + u0 + uq * 4 + qq) * B_ + eb];
  }

  for (int tl = 0; tl < CH_; tl++) {
    int t = t0 + tl;
    int pp = t & 1;
    const char* srcHi = (const char*)(hhi + (size_t)(pp * 2 + dir) * B_ * H_);
    const char* srcLo = (const char*)(hlo + (size_t)(pp * 2 + dir) * B_ * H_);
    char* dstHi = (char*)(hhi + (size_t)((pp ^ 1) * 2 + dir) * B_ * H_);
    char* dstLo = (char*)(hlo + (size_t)((pp ^ 1) * 2 + dir) * B_ * H_);

    // ---- async stage h (hi+lo) into LDS, device-scope (aux=16 -> SC1):
    //      bypasses this XCD's (stale) L2, reads fresh data from LLC ----
    {
      int sof = g * 16384 + lane * 16;
#pragma unroll
      for (int it = 0; it < 16; it++) {
        __builtin_amdgcn_global_load_lds((GChar*)(srcHi + sof + it * 1024),
                                         (LChar*)(lbuf + sof + it * 1024), 16, 0, 16);
        __builtin_amdgcn_global_load_lds((GChar*)(srcLo + sof + it * 1024),
                                         (LChar*)(lbuf + 65536 + sof + it * 1024), 16, 0, 16);
      }
    }
    __syncthreads();   // drains vmcnt(0): all waves' staging complete

    // ---- prefetch next step's xp into regs (independent of h; lands during MFMA) ----
    float xqn[16];
    if (tl < CH_ - 1) {
      const float* xpn = xpb + (size_t)(tl + 1) * G4_ * B_;
#pragma unroll
      for (int q2 = 0; q2 < 16; q2++) {
        int gg = q2 >> 2, qq = q2 & 3;
        xqn[q2] = xpn[(size_t)(gg * H_ + u0 + uq * 4 + qq) * B_ + eb];
      }
    }

    // ---- MFMA from LDS ----
    f32x4 aH[4], aX[4];
#pragma unroll
    for (int bt = 0; bt < 4; bt++) {
      f32x4 z = {0.f, 0.f, 0.f, 0.f};
      aH[bt] = z; aX[bt] = z;
    }
#pragma unroll
    for (int kt = 0; kt < 16; kt++) {
#pragma unroll
      for (int bt = 0; bt < 4; bt++) {
        int row = bt * 16 + lm;
        int p = (row * 1024 + kt * 64 + kb) ^ ((lm & 15) << 4);
        s8v ah = *(const s8v*)(lbuf + p);
        s8v al = *(const s8v*)(lbuf + 65536 + p);
        aH[bt] = __builtin_amdgcn_mfma_f32_16x16x32_bf16(ah, bh[kt], aH[bt], 0, 0, 0);
        aX[bt] = __builtin_amdgcn_mfma_f32_16x16x32_bf16(al, bh[kt], aX[bt], 0, 0, 0);
        aX[bt] = __builtin_amdgcn_mfma_f32_16x16x32_bf16(ah, bl[kt], aX[bt], 0, 0, 0);
      }
    }
    __syncthreads();   // all fragment reads done -> safe to overwrite front of lbuf (glx)
#pragma unroll
    for (int bt = 0; bt < 4; bt++) {
#pragma unroll
      for (int jj = 0; jj < 4; jj++) {
        int brow = bt * 16 + (lane >> 4) * 4 + jj;
        glx[(g * 16 + lm) * 65 + brow] = aH[bt][jj] + aX[bt][jj];
      }
    }
    __syncthreads();

    // ---- epilogue ----
    if (t < len) {
      float hn[4];
#pragma unroll
      for (int q = 0; q < 4; q++) {
        int ul = uq * 4 + q;
        float iv = glx[(0 * 16 + ul) * 65 + eb] + xq[0 * 4 + q];
        float fv = glx[(1 * 16 + ul) * 65 + eb] + xq[1 * 4 + q];
        float gv = glx[(2 * 16 + ul) * 65 + eb] + xq[2 * 4 + q];
        float ov = glx[(3 * 16 + ul) * 65 + eb] + xq[3 * 4 + q];
        float si = 1.f / (1.f + expf(-iv));
        float sf = 1.f / (1.f + expf(-fv));
        float so = 1.f / (1.f + expf(-ov));
        float cn = sf * creg[q] + si * tanhf(gv);
        creg[q] = cn;
        hn[q] = so * tanhf(cn);
      }
      ushort4 hi4, lo4;
      unsigned short h0 = f2bf_rne(hn[0]); unsigned short l0 = f2bf_rne(hn[0] - bf2f(h0));
      unsigned short h1 = f2bf_rne(hn[1]); unsigned short l1 = f2bf_rne(hn[1] - bf2f(h1));
      unsigned short h2 = f2bf_rne(hn[2]); unsigned short l2 = f2bf_rne(hn[2] - bf2f(h2));
      unsigned short h3 = f2bf_rne(hn[3]); unsigned short l3 = f2bf_rne(hn[3] - bf2f(h3));
      hi4.x = h0; hi4.y = h1; hi4.z = h2; hi4.w = h3;
      lo4.x = l0; lo4.y = l1; lo4.z = l2; lo4.w = l3;
      __hip_atomic_store((unsigned long long*)(dstHi + pby),
                         __builtin_bit_cast(unsigned long long, hi4),
                         __ATOMIC_RELAXED, __HIP_MEMORY_SCOPE_AGENT);
      __hip_atomic_store((unsigned long long*)(dstLo + pby),
                         __builtin_bit_cast(unsigned long long, lo4),
                         __ATOMIC_RELAXED, __HIP_MEMORY_SCOPE_AGENT);
      float4 hv; hv.x = hn[0]; hv.y = hn[1]; hv.z = hn[2]; hv.w = hn[3];
      if (dir == 0) *(float4*)(out + ((size_t)t * B_ + eb) * HD_ + u0 + uq * 4) = hv;
      else          *(float4*)(out + ((size_t)(len - 1 - t) * B_ + eb) * HD_ + H_ + u0 + uq * 4) = hv;
    } else {
      unsigned long long vh = __hip_atomic_load((const unsigned long long*)(srcHi + pby),
                                                __ATOMIC_RELAXED, __HIP_MEMORY_SCOPE_AGENT);
      unsigned long long vl = __hip_atomic_load((const unsigned long long*)(srcLo + pby),
                                                __ATOMIC_RELAXED, __HIP_MEMORY_SCOPE_AGENT);
      __hip_atomic_store((unsigned long long*)(dstHi + pby), vh,
                         __ATOMIC_RELAXED, __HIP_MEMORY_SCOPE_AGENT);
      __hip_atomic_store((unsigned long long*)(dstLo + pby), vl,
                         __ATOMIC_RELAXED, __HIP_MEMORY_SCOPE_AGENT);
      if (dir == 0) {
        float4 z; z.x = z.y = z.z = z.w = 0.f;
        *(float4*)(out + ((size_t)t * B_ + eb) * HD_ + u0 + uq * 4) = z;
      }
    }
#pragma unroll
    for (int q2 = 0; q2 < 16; q2++) xq[q2] = xqn[q2];
    if (tl != CH_ - 1) gridbar(flags, wg, (unsigned)(tl + 1));
  }
  *(float4*)(cbuf + coff) = *(const float4*)creg;
}

// ---------------- emission heads ----------------
__global__ void k_em0(const float* __restrict__ o, const float* __restrict__ w,
                      const float* __restrict__ bias, float* __restrict__ em) {
  int gt = blockIdx.x * blockDim.x + threadIdx.x;
  int wid = gt >> 6;
  int lane = threadIdx.x & 63;
  if (wid >= T_ * B_) return;
  const float* row = o + (size_t)wid * HD_;
  float r[16];
#pragma unroll
  for (int q = 0; q < 16; q++) r[q] = row[lane + 64 * q];
  for (int c = 0; c < 13; c++) {
    const float* wr = w + (size_t)c * HD_;
    float p = 0.f;
#pragma unroll
    for (int q = 0; q < 16; q++) p += r[q] * wr[lane + 64 * q];
    for (int off = 32; off > 0; off >>= 1) p += __shfl_down(p, off);
    if (lane == 0) em[(size_t)wid * 16 + c] = p + bias[c];
  }
}

__global__ void k_em1(const float* __restrict__ o, const float* __restrict__ w,
                      const float* __restrict__ bias, const int* __restrict__ tags0,
                      float* __restrict__ em) {
  int gt = blockIdx.x * blockDim.x + threadIdx.x;
  int wid = gt >> 6;
  int lane = threadIdx.x & 63;
  if (wid >= T_ * B_) return;
  int t = wid / B_, b = wid % B_;
  float tag = (float)tags0[b * T_ + t];
  const float* row = o + (size_t)wid * HD_;
  float r[16];
#pragma unroll
  for (int q = 0; q < 16; q++) r[q] = row[lane + 64 * q];
  for (int c = 0; c < 25; c++) {
    const float* wr = w + (size_t)c * 1025;
    float p = 0.f;
#pragma unroll
    for (int q = 0; q < 16; q++) p += r[q] * wr[lane + 64 * q];
    for (int off = 32; off > 0; off >>= 1) p += __shfl_down(p, off);
    if (lane == 0) em[(size_t)wid * 32 + c] = p + wr[1024] * tag + bias[c];
  }
}

// ---------------- Viterbi (one block per batch element) ----------------
template <int L, int LD>
__global__ void k_viterbi(const float* __restrict__ em, const int* __restrict__ lens,
                          const float* __restrict__ startv, const float* __restrict__ endv,
                          const float* __restrict__ trans, int* __restrict__ hist,
                          int* __restrict__ tags) {
  int b = blockIdx.x;
  int j = threadIdx.x;
  __shared__ float sc[L];
  __shared__ float trT[L * L];
  int len = lens[b];
  if (j < L) {
    sc[j] = startv[j] + em[(size_t)b * LD + j];
    for (int i = 0; i < L; i++) trT[j * L + i] = trans[i * L + j];
  }
  __syncthreads();
  for (int t = 1; t < len; t++) {
    float nv = 0.f; int bi = 0;
    if (j < L) {
      float best = sc[0] + trT[j * L + 0];
      for (int i = 1; i < L; i++) {
        float v = sc[i] + trT[j * L + i];
        if (v > best) { best = v; bi = i; }
      }
      nv = best + em[((size_t)t * B_ + b) * LD + j];
      hist[((size_t)b * T_ + t) * LD + j] = bi;
    }
    __syncthreads();
    if (j < L) sc[j] = nv;
    __syncthreads();
  }
  if (j == 0) {
    float best = sc[0] + endv[0]; int bi = 0;
    for (int i = 1; i < L; i++) {
      float v = sc[i] + endv[i];
      if (v > best) { best = v; bi = i; }
    }
    int tag = bi;
    tags[b * T_ + (len - 1)] = tag;
    for (int t = len - 2; t >= 0; t--) {
      tag = hist[((size_t)b * T_ + (t + 1)) * LD + tag];
      tags[b * T_ + t] = tag;
    }
    for (int t = len; t < T_; t++) tags[b * T_ + t] = 0;
  }
}

// ---------------- host ----------------
extern "C" void kernel_launch(void* const* d_in, const int* in_sizes, int n_in,
                              void* d_out, int out_size, void* d_ws, size_t ws_size,
                              hipStream_t stream) {
  const int*   word = (const int*)d_in[0];
  const float* emb  = (const float*)d_in[1];
  const float* w0ih = (const float*)d_in[2];
  const float* w0hh = (const float*)d_in[3];
  const float* b0   = (const float*)d_in[4];
  const float* w1ih = (const float*)d_in[5];
  const float* w1hh = (const float*)d_in[6];
  const float* b1   = (const float*)d_in[7];
  const float* h0w  = (const float*)d_in[8];
  const float* h0b  = (const float*)d_in[9];
  const float* h1w  = (const float*)d_in[10];
  const float* h1b  = (const float*)d_in[11];
  const float* c0s  = (const float*)d_in[12];
  const float* c0e  = (const float*)d_in[13];
  const float* c0t  = (const float*)d_in[14];
  const float* c1s  = (const float*)d_in[15];
  const float* c1e  = (const float*)d_in[16];
  const float* c1t  = (const float*)d_in[17];

  int* out_tags0 = (int*)d_out;
  int* out_tags1 = out_tags0 + B_ * T_;
  int* out_len   = out_tags1 + B_ * T_;

  char* ws = (char*)d_ws;
  size_t off = 0;
  auto alloc = [&](size_t bytes) -> void* {
    void* p = ws + off;
    off += (bytes + 255) & ~(size_t)255;
    return p;
  };
  int*   lens  = (int*)alloc(B_ * 4);
  unsigned* flags = (unsigned*)alloc(256);
  float* x     = (float*)alloc((size_t)T_ * B_ * D_ * 4);
  float* out0  = (float*)alloc((size_t)T_ * B_ * HD_ * 4);
  float* out1  = (float*)alloc((size_t)T_ * B_ * HD_ * 4);
  float* xpf   = (float*)alloc((size_t)CH_ * B_ * G4_ * 4);
  float* xpr   = (float*)alloc((size_t)CH_ * B_ * G4_ * 4);
  unsigned short* hhi = (unsigned short*)alloc((size_t)2 * 2 * B_ * H_ * 2);  // pingpong x dir
  unsigned short* hlo = (unsigned short*)alloc((size_t)2 * 2 * B_ * H_ * 2);
  float* cbuf  = (float*)alloc((size_t)2 * B_ * H_ * 4);
  unsigned short* w0hh_hi = (unsigned short*)alloc((size_t)2 * G4_ * H_ * 2);
  unsigned short* w0hh_lo = (unsigned short*)alloc((size_t)2 * G4_ * H_ * 2);
  unsigned short* w1hh_hi = (unsigned short*)alloc((size_t)2 * G4_ * H_ * 2);
  unsigned short* w1hh_lo = (unsigned short*)alloc((size_t)2 * G4_ * H_ * 2);
  float* em0   = (float*)alloc((size_t)T_ * B_ * 16 * 4);
  float* em1   = (float*)alloc((size_t)T_ * B_ * 32 * 4);
  int*   hist0 = (int*)alloc((size_t)B_ * T_ * 16 * 4);
  int*   hist1 = (int*)alloc((size_t)B_ * T_ * 32 * 4);
  (void)ws_size; (void)in_sizes; (void)n_in; (void)out_size;

  hipMemsetAsync(out0, 0, (size_t)T_ * B_ * HD_ * 4, stream);
  hipMemsetAsync(out1, 0, (size_t)T_ * B_ * HD_ * 4, stream);

  k_lengths<<<B_, 256, 0, stream>>>(word, lens, out_len);
  {
    int total = T_ * B_ * (D_ / 4);
    k_embed<<<(total + 255) / 256, 256, 0, stream>>>(word, emb, x);
  }
  {
    int n = 2 * G4_ * H_;
    k_split<<<(n + 255) / 256, 256, 0, stream>>>(w0hh, w0hh_hi, w0hh_lo, n);
    k_split<<<(n + 255) / 256, 256, 0, stream>>>(w1hh, w1hh_hi, w1hh_lo, n);
  }

  for (int layer = 0; layer < 2; layer++) {
    const float* src = (layer == 0) ? x : out0;
    int K = (layer == 0) ? D_ : HD_;
    const float* wih = (layer == 0) ? w0ih : w1ih;
    const float* bb  = (layer == 0) ? b0 : b1;
    const unsigned short* whi = (layer == 0) ? w0hh_hi : w1hh_hi;
    const unsigned short* wlo = (layer == 0) ? w0hh_lo : w1hh_lo;
    float* outbuf = (layer == 0) ? out0 : out1;
    hipMemsetAsync(hhi, 0, (size_t)2 * 2 * B_ * H_ * 2, stream);
    hipMemsetAsync(hlo, 0, (size_t)2 * 2 * B_ * H_ * 2, stream);
    hipMemsetAsync(cbuf, 0, (size_t)2 * B_ * H_ * 4, stream);
    for (int cch = 0; cch < T_ / CH_; cch++) {
      dim3 grid(CH_, G4_ / 64);
      k_proj<<<grid, 256, 0, stream>>>(src, wih, bb, xpf, lens, K, cch * CH_, 0);
      k_proj<<<grid, 256, 0, stream>>>(src, wih + (size_t)G4_ * K, bb + G4_, xpr, lens, K, cch * CH_, 1);
      hipMemsetAsync(flags, 0, 256, stream);
      k_lstm_chunk<<<NWG_, 256, 0, stream>>>(whi, wlo, xpf, xpr, lens, hhi, hlo,
                                             cbuf, outbuf, cch * CH_, flags);
    }
  }

  k_em0<<<(T_ * B_) / 4, 256, 0, stream>>>(out1, h0w, h0b, em0);
  k_viterbi<13, 16><<<B_, 64, 0, stream>>>(em0, lens, c0s, c0e, c0t, hist0, out_tags0);
  k_em1<<<(T_ * B_) / 4, 256, 0, stream>>>(out1, h1w, h1b, out_tags0, em1);
  k_viterbi<25, 32><<<B_, 64, 0, stream>>>(em1, lens, c1s, c1e, c1t, hist1, out_tags1);
}